// Round 7
// baseline (140.536 us; speedup 1.0000x reference)
//
#include <hip/hip_runtime.h>
#include <math.h>

// Problem constants
#define NXD 64
#define NYD 48
#define NZD 32
#define NPT (NXD*NYD*NZD)   // 98304 points
#define PN  10              // neighbors per point
#define MF  5               // fourier modes
#define H1  64
#define H2  32
#define H3  8

// Block geometry: 256 threads = 4 waves; 32 points = 320 rows per block;
// each wave owns 8 points = 80 rows = 5 tiles of 16 rows.
#define PTS_PER_BLOCK 32
#define ROWS_PER_BLOCK (PTS_PER_BLOCK*PN)   // 320
#define TILES_PER_WAVE 5

// LDS row strides (bf16 elems) — multiples of 8 so rows are 16B-aligned for b128
#define A2S 72   // 16 rows x 72 (64 ch + pad)
#define A3S 40   // 16 rows x 40 (32 ch + pad) — aliased into a2buf space (R6-validated)

typedef __attribute__((ext_vector_type(8))) short short8;  // 8 bf16 = 4 VGPRs
typedef __attribute__((ext_vector_type(4))) float f32x4;

extern "C" __device__ float __ocml_exp2_f32(float);

// exact RNE fp32->bf16 (one-time weight conversion only)
__device__ __forceinline__ short f2bf(float f) {
    unsigned u = __float_as_uint(f);
    unsigned r = (u + 0x7fffu + ((u >> 16) & 1u)) >> 16;
    return (short)r;
}
// fast fp32->bf16 (round-half-up): 2 VALU
__device__ __forceinline__ unsigned short f2bf_hu(float f) {
    return (unsigned short)((__float_as_uint(f) + 0x8000u) >> 16);
}
// pack two fp32 -> one dword of 2 bf16 (lo in low half): 2 adds + v_perm
__device__ __forceinline__ unsigned pack2_bf16(float lo, float hi) {
    return __builtin_amdgcn_perm(__float_as_uint(hi) + 0x8000u,
                                 __float_as_uint(lo) + 0x8000u, 0x07060302u);
}

// GELU (tanh-form, sigma rewrite, log2e folded):
//   gelu(x) = x * rcp(1 + exp2(x * (-2.30220846 - 0.10294296 x^2)))
// Quad version shares ONE v_rcp across 4 evals (exact product identity):
//   1/Di = (prod of other Dj) * rcp(prod Dj)
// exp2 arg clamped at +30 so the 4-term product stays < 1.3e36 (no overflow);
// clamp changes nothing numerically for rcp (2^30 vs larger -> result ~0 either way).
__device__ __forceinline__ f32x4 gelu_quad(f32x4 v) {
    f32x4 D;
    #pragma unroll
    for (int r = 0; r < 4; ++r) {
        float x2 = v[r] * v[r];
        float p  = __builtin_fmaf(-0.10294296f, x2, -2.30220846f);
        float t  = fminf(v[r] * p, 30.0f);
        D[r] = __ocml_exp2_f32(t) + 1.0f;
    }
    float q0  = D[0] * D[1];
    float q1  = D[2] * D[3];
    float R   = __builtin_amdgcn_rcpf(q0 * q1);
    float q1R = q1 * R;
    float q0R = q0 * R;
    f32x4 g;
    g[0] = v[0] * (D[1] * q1R);
    g[1] = v[1] * (D[0] * q1R);
    g[2] = v[2] * (D[3] * q0R);
    g[3] = v[3] * (D[2] * q0R);
    return g;
}
// tanh(v) = 2*rcp(1+e^{-2v}) - 1, quad-shared rcp as above
__device__ __forceinline__ f32x4 tanh_quad(f32x4 v) {
    f32x4 D;
    #pragma unroll
    for (int r = 0; r < 4; ++r) {
        float t = fminf(v[r] * -2.88539008f, 30.0f);
        D[r] = __ocml_exp2_f32(t) + 1.0f;
    }
    float q0  = D[0] * D[1];
    float q1  = D[2] * D[3];
    float R   = __builtin_amdgcn_rcpf(q0 * q1);
    float q1R = q1 * R;
    float q0R = q0 * R;
    f32x4 o;
    o[0] = __builtin_fmaf(2.0f, D[1] * q1R, -1.0f);
    o[1] = __builtin_fmaf(2.0f, D[0] * q1R, -1.0f);
    o[2] = __builtin_fmaf(2.0f, D[3] * q0R, -1.0f);
    o[3] = __builtin_fmaf(2.0f, D[2] * q0R, -1.0f);
    return o;
}

__global__ __launch_bounds__(256) void domino_mfma_kernel(
    const float* __restrict__ x,      // (NPT*PN, 3)
    const float* __restrict__ freqs,  // (MF,)
    const float* __restrict__ W1,     // (33, 64)
    const float* __restrict__ b1,
    const float* __restrict__ W2,     // (64, 32)
    const float* __restrict__ b2,
    const float* __restrict__ W3,     // (32, 8)
    const float* __restrict__ b3,
    float* __restrict__ out)          // (8, NPT)
{
    __shared__ float obuf[ROWS_PER_BLOCK * 9];                  // masked tanh rows
    __shared__ __align__(16) unsigned short a2buf[4][16 * A2S]; // L1->L2 transpose; a3 aliased inside
    __shared__ __align__(16) float mcx[4][16];   // x-coordinate per row (mask)
    __shared__ __align__(16) float mv32[4][16];  // feature ch32 = cos(f4*z) per row

    const int tid  = threadIdx.x;
    const int w    = tid >> 6;      // wave id 0..3
    const int lane = tid & 63;
    const int lr   = lane & 15;     // A-row / B-col / C-col index
    const int lg   = lane >> 4;     // k-group / C-row-group

    // ---- frequencies
    float fr[MF];
    #pragma unroll
    for (int m = 0; m < MF; ++m) fr[m] = freqs[m];

    // ---- preload weight fragments (once per wave)
    // B layout for 16x16x32: n = lane&15, k = (lane>>4)*8 + j
    short8 B1f[4];                      // layer1: K=32 (ch0..31), N=64 -> 4 n-tiles
    float  w32[4], bv1[4];              // ch32 rank-1 fixup weights + bias
    #pragma unroll
    for (int t1 = 0; t1 < 4; ++t1) {
        #pragma unroll
        for (int j = 0; j < 8; ++j)
            B1f[t1][j] = f2bf(W1[(lg*8 + j)*H1 + t1*16 + lr]);
        w32[t1] = W1[32*H1 + t1*16 + lr];
        bv1[t1] = b1[t1*16 + lr];
    }
    short8 B2f[2][2];                   // layer2: K=64 (2 steps), N=32 -> 2 n-tiles
    float  bv2[2];
    #pragma unroll
    for (int s = 0; s < 2; ++s)
        #pragma unroll
        for (int t2 = 0; t2 < 2; ++t2)
            #pragma unroll
            for (int j = 0; j < 8; ++j)
                B2f[s][t2][j] = f2bf(W2[(s*32 + lg*8 + j)*H2 + t2*16 + lr]);
    #pragma unroll
    for (int t2 = 0; t2 < 2; ++t2) bv2[t2] = b2[t2*16 + lr];

    short8 B3f;                         // layer3: K=32, N=16 (cols 8..15 zero)
    float  bv3 = (lr < H3) ? b3[lr] : 0.0f;
    #pragma unroll
    for (int j = 0; j < 8; ++j)
        B3f[j] = (lr < H3) ? f2bf(W3[(lg*8 + j)*H3 + lr]) : (short)0;

    const int wrow0 = blockIdx.x * ROWS_PER_BLOCK + w * (TILES_PER_WAVE*16);

    #pragma unroll 1
    for (int t = 0; t < TILES_PER_WAVE; ++t) {
        const int myrow = wrow0 + t*16 + lr;  // the A-row this lane generates

        // ---- load coords (4 lane-groups read the same 12B; L1 broadcast)
        const float* xp = x + (size_t)myrow * 3;
        const float cx = xp[0], cy = xp[1], cz = xp[2];

        // ---- all sin/cos: index m*3+d
        float sv[15], cv[15];
        #pragma unroll
        for (int m = 0; m < MF; ++m) {
            __sincosf(fr[m]*cx, &sv[m*3+0], &cv[m*3+0]);
            __sincosf(fr[m]*cy, &sv[m*3+1], &cv[m*3+1]);
            __sincosf(fr[m]*cz, &sv[m*3+2], &cv[m*3+2]);
        }

        // stage per-row mask coord and feature ch32 = cv[14]
        if (lg == 0) { mcx[w][lr] = cx; mv32[w][lr] = cv[14]; }

        // ---- select this lane's 8 feature channels k = lg*8 .. lg*8+7
        float fv[8];
        if (lg == 0) {
            fv[0]=cx; fv[1]=cy; fv[2]=cz;
            fv[3]=sv[0]; fv[4]=sv[1]; fv[5]=sv[2]; fv[6]=sv[3]; fv[7]=sv[4];
        } else if (lg == 1) {
            fv[0]=sv[5];  fv[1]=sv[6];  fv[2]=sv[7];  fv[3]=sv[8];
            fv[4]=sv[9];  fv[5]=sv[10]; fv[6]=sv[11]; fv[7]=sv[12];
        } else if (lg == 2) {
            fv[0]=sv[13]; fv[1]=sv[14]; fv[2]=cv[0];  fv[3]=cv[1];
            fv[4]=cv[2];  fv[5]=cv[3];  fv[6]=cv[4];  fv[7]=cv[5];
        } else {
            fv[0]=cv[6];  fv[1]=cv[7];  fv[2]=cv[8];  fv[3]=cv[9];
            fv[4]=cv[10]; fv[5]=cv[11]; fv[6]=cv[12]; fv[7]=cv[13];
        }
        union { unsigned u[4]; short8 s8; } a1u;
        #pragma unroll
        for (int j = 0; j < 4; ++j) a1u.u[j] = pack2_bf16(fv[2*j], fv[2*j+1]);
        const short8 a1 = a1u.s8;

        // ---- Layer 1: 4 n-tiles, K=32, bias-initialized accumulators
        f32x4 c1[4];
        #pragma unroll
        for (int t1 = 0; t1 < 4; ++t1) {
            f32x4 ci = {bv1[t1], bv1[t1], bv1[t1], bv1[t1]};
            c1[t1] = __builtin_amdgcn_mfma_f32_16x16x32_bf16(a1, B1f[t1], ci, 0, 0, 0);
        }
        // ch32 rank-1 fixup + mask coords for this lane's 4 C-rows (float4 LDS reads)
        const f32x4 v32r = *(const f32x4*)&mv32[w][lg*4];
        const f32x4 mxr  = *(const f32x4*)&mcx[w][lg*4];
        #pragma unroll
        for (int t1 = 0; t1 < 4; ++t1)
            #pragma unroll
            for (int r = 0; r < 4; ++r)
                c1[t1][r] = __builtin_fmaf(v32r[r], w32[t1], c1[t1][r]);
        #pragma unroll
        for (int t1 = 0; t1 < 4; ++t1)
            c1[t1] = gelu_quad(c1[t1]);

        // ---- transpose L1 out (C-layout) -> A-layout via LDS
        #pragma unroll
        for (int t1 = 0; t1 < 4; ++t1)
            #pragma unroll
            for (int r = 0; r < 4; ++r)
                a2buf[w][(lg*4 + r)*A2S + t1*16 + lr] = f2bf_hu(c1[t1][r]);
        short8 a2f[2];
        #pragma unroll
        for (int s = 0; s < 2; ++s)
            a2f[s] = *(const short8*)&a2buf[w][lr*A2S + s*32 + lg*8];

        // ---- Layer 2: K=64 (2 steps), 2 n-tiles
        f32x4 c2[2];
        #pragma unroll
        for (int t2 = 0; t2 < 2; ++t2) {
            f32x4 ci = {bv2[t2], bv2[t2], bv2[t2], bv2[t2]};
            ci = __builtin_amdgcn_mfma_f32_16x16x32_bf16(a2f[0], B2f[0][t2], ci, 0, 0, 0);
            c2[t2] = __builtin_amdgcn_mfma_f32_16x16x32_bf16(a2f[1], B2f[1][t2], ci, 0, 0, 0);
        }
        #pragma unroll
        for (int t2 = 0; t2 < 2; ++t2)
            c2[t2] = gelu_quad(c2[t2]);

        // ---- transpose L2 out -> A-layout, aliased into a2buf space.
        // Safe: a2f reads complete (data dep through MFMA) before these writes issue;
        // same-wave DS ops process in order. (R6-validated.)
        unsigned short* a3p = &a2buf[w][0];
        #pragma unroll
        for (int t2 = 0; t2 < 2; ++t2)
            #pragma unroll
            for (int r = 0; r < 4; ++r)
                a3p[(lg*4 + r)*A3S + t2*16 + lr] = f2bf_hu(c2[t2][r]);
        const short8 a3f = *(const short8*)&a3p[lr*A3S + lg*8];

        // ---- Layer 3: K=32, N=16 (8 valid)
        f32x4 c3 = {bv3, bv3, bv3, bv3};
        c3 = __builtin_amdgcn_mfma_f32_16x16x32_bf16(a3f, B3f, c3, 0, 0, 0);

        // ---- tanh (quad-rcp), mask, store per-row result to block buffer
        const f32x4 th = tanh_quad(c3);
        #pragma unroll
        for (int r = 0; r < 4; ++r) {
            const int brow = w*(TILES_PER_WAVE*16) + t*16 + lg*4 + r;
            const float mk = (fabsf(mxr[r]) > 1e-6f) ? 1.0f : 0.0f;
            if (lr < H3) obuf[brow*9 + lr] = mk * th[r];
        }
    }

    __syncthreads();

    // ---- neighbor reduction: 32 points x 8 channels; coalesced final store
    {
        const int p  = tid & 31;   // consecutive lanes -> consecutive out addresses
        const int ch = tid >> 5;   // 0..7
        float sum = 0.0f;
        #pragma unroll
        for (int i = 0; i < PN; ++i) sum += obuf[(p*PN + i)*9 + ch];
        const int gp = blockIdx.x * PTS_PER_BLOCK + p;
        out[(size_t)ch * NPT + gp] = sum;
    }
}

extern "C" void kernel_launch(void* const* d_in, const int* in_sizes, int n_in,
                              void* d_out, int out_size, void* d_ws, size_t ws_size,
                              hipStream_t stream) {
    // setup_inputs order: x, grid(unused), freqs, W1, b1, W2, b2, W3, b3
    const float* x     = (const float*)d_in[0];
    const float* freqs = (const float*)d_in[2];
    const float* W1    = (const float*)d_in[3];
    const float* b1    = (const float*)d_in[4];
    const float* W2    = (const float*)d_in[5];
    const float* b2    = (const float*)d_in[6];
    const float* W3    = (const float*)d_in[7];
    const float* b3    = (const float*)d_in[8];
    float* out = (float*)d_out;

    const int grid = NPT / PTS_PER_BLOCK;   // 3072 blocks, no remainder
    domino_mfma_kernel<<<grid, 256, 0, stream>>>(x, freqs, W1, b1, W2, b2, W3, b3, out);
}

// Round 8
// 128.231 us; speedup vs baseline: 1.0960x; 1.0960x over previous
//
#include <hip/hip_runtime.h>
#include <math.h>

// Problem constants
#define NXD 64
#define NYD 48
#define NZD 32
#define NPT (NXD*NYD*NZD)   // 98304 points
#define PN  10              // neighbors per point
#define MF  5               // fourier modes
#define H1  64
#define H2  32
#define H3  8

// Block geometry: 256 threads = 4 waves; 32 points = 320 rows per block;
// each wave owns 8 points = 80 rows = 5 tiles of 16 rows.
#define PTS_PER_BLOCK 32
#define ROWS_PER_BLOCK (PTS_PER_BLOCK*PN)   // 320
#define TILES_PER_WAVE 5

// LDS row strides (bf16 elems) — multiples of 8 so rows are 16B-aligned for b128
#define A2S 72   // 16 rows x 72 (64 ch + pad)
#define A3S 40   // 16 rows x 40 (32 ch + pad) — ALIASED into a2buf space (single R8 delta)

typedef __attribute__((ext_vector_type(8))) short short8;  // 8 bf16 = 4 VGPRs
typedef __attribute__((ext_vector_type(4))) float f32x4;

// exact RNE fp32->bf16 (used only for one-time weight conversion)
__device__ __forceinline__ short f2bf(float f) {
    unsigned u = __float_as_uint(f);
    unsigned r = (u + 0x7fffu + ((u >> 16) & 1u)) >> 16;
    return (short)r;
}

// fast fp32->bf16, round-to-nearest (half-up on exact ties): 2 VALU
__device__ __forceinline__ unsigned short f2bf_hu(float f) {
    return (unsigned short)((__float_as_uint(f) + 0x8000u) >> 16);
}

// pack two fp32 -> one dword of 2 bf16 (lo in low half): 2 adds + v_perm
__device__ __forceinline__ unsigned pack2_bf16(float lo, float hi) {
    return __builtin_amdgcn_perm(__float_as_uint(hi) + 0x8000u,
                                 __float_as_uint(lo) + 0x8000u, 0x07060302u);
}

// tanh-form GELU via hw exp+rcp: gelu = x - x/(1+e^{2u}), 2u = 1.5957691(x+0.044715x^3)
// approx error ~3e-4 vs exact erf-gelu; saturates correctly
__device__ __forceinline__ float gelu_fast(float x) {
    float x2 = x * x;
    float t  = x * (1.59576912f + 0.07135482f * x2);
    float E  = __expf(t);
    return x - x * __builtin_amdgcn_rcpf(E + 1.0f);
}

// tanh via hw exp+rcp: 1 - 2/(1+e^{2v}); safe at both infinities
__device__ __forceinline__ float tanh_fast(float v) {
    float E = __expf(2.0f * v);
    return 1.0f - 2.0f * __builtin_amdgcn_rcpf(E + 1.0f);
}

__global__ __launch_bounds__(256) void domino_mfma_kernel(
    const float* __restrict__ x,      // (NPT*PN, 3)
    const float* __restrict__ freqs,  // (MF,)
    const float* __restrict__ W1,     // (33, 64)
    const float* __restrict__ b1,
    const float* __restrict__ W2,     // (64, 32)
    const float* __restrict__ b2,
    const float* __restrict__ W3,     // (32, 8)
    const float* __restrict__ b3,
    float* __restrict__ out)          // (8, NPT)
{
    __shared__ float obuf[ROWS_PER_BLOCK * 9];                  // masked tanh rows
    __shared__ __align__(16) unsigned short a2buf[4][16 * A2S]; // L1->L2 transpose; a3 aliased inside
    __shared__ __align__(16) float mcx[4][16];   // x-coordinate per row (mask)
    __shared__ __align__(16) float mv32[4][16];  // feature ch32 = cos(f4*z) per row

    const int tid  = threadIdx.x;
    const int w    = tid >> 6;      // wave id 0..3
    const int lane = tid & 63;
    const int lr   = lane & 15;     // A-row / B-col / C-col index
    const int lg   = lane >> 4;     // k-group / C-row-group

    // ---- frequencies
    float fr[MF];
    #pragma unroll
    for (int m = 0; m < MF; ++m) fr[m] = freqs[m];

    // ---- preload weight fragments (once per wave)
    // B layout for 16x16x32: n = lane&15, k = (lane>>4)*8 + j
    short8 B1f[4];                      // layer1: K=32 (ch0..31), N=64 -> 4 n-tiles
    float  w32[4], bv1[4];              // ch32 rank-1 fixup weights + bias
    #pragma unroll
    for (int t1 = 0; t1 < 4; ++t1) {
        #pragma unroll
        for (int j = 0; j < 8; ++j)
            B1f[t1][j] = f2bf(W1[(lg*8 + j)*H1 + t1*16 + lr]);
        w32[t1] = W1[32*H1 + t1*16 + lr];
        bv1[t1] = b1[t1*16 + lr];
    }
    short8 B2f[2][2];                   // layer2: K=64 (2 steps), N=32 -> 2 n-tiles
    float  bv2[2];
    #pragma unroll
    for (int s = 0; s < 2; ++s)
        #pragma unroll
        for (int t2 = 0; t2 < 2; ++t2)
            #pragma unroll
            for (int j = 0; j < 8; ++j)
                B2f[s][t2][j] = f2bf(W2[(s*32 + lg*8 + j)*H2 + t2*16 + lr]);
    #pragma unroll
    for (int t2 = 0; t2 < 2; ++t2) bv2[t2] = b2[t2*16 + lr];

    short8 B3f;                         // layer3: K=32, N=16 (cols 8..15 zero)
    float  bv3 = (lr < H3) ? b3[lr] : 0.0f;
    #pragma unroll
    for (int j = 0; j < 8; ++j)
        B3f[j] = (lr < H3) ? f2bf(W3[(lg*8 + j)*H3 + lr]) : (short)0;

    const int wrow0 = blockIdx.x * ROWS_PER_BLOCK + w * (TILES_PER_WAVE*16);

    #pragma unroll 1
    for (int t = 0; t < TILES_PER_WAVE; ++t) {
        const int myrow = wrow0 + t*16 + lr;  // the A-row this lane generates

        // ---- load coords (4 lane-groups read the same 12B; L1 broadcast)
        const float* xp = x + (size_t)myrow * 3;
        const float cx = xp[0], cy = xp[1], cz = xp[2];

        // ---- all sin/cos: index m*3+d
        float sv[15], cv[15];
        #pragma unroll
        for (int m = 0; m < MF; ++m) {
            __sincosf(fr[m]*cx, &sv[m*3+0], &cv[m*3+0]);
            __sincosf(fr[m]*cy, &sv[m*3+1], &cv[m*3+1]);
            __sincosf(fr[m]*cz, &sv[m*3+2], &cv[m*3+2]);
        }

        // stage per-row mask coord and feature ch32 = cv[14]
        if (lg == 0) { mcx[w][lr] = cx; mv32[w][lr] = cv[14]; }

        // ---- select this lane's 8 feature channels k = lg*8 .. lg*8+7
        float fv[8];
        if (lg == 0) {
            fv[0]=cx; fv[1]=cy; fv[2]=cz;
            fv[3]=sv[0]; fv[4]=sv[1]; fv[5]=sv[2]; fv[6]=sv[3]; fv[7]=sv[4];
        } else if (lg == 1) {
            fv[0]=sv[5];  fv[1]=sv[6];  fv[2]=sv[7];  fv[3]=sv[8];
            fv[4]=sv[9];  fv[5]=sv[10]; fv[6]=sv[11]; fv[7]=sv[12];
        } else if (lg == 2) {
            fv[0]=sv[13]; fv[1]=sv[14]; fv[2]=cv[0];  fv[3]=cv[1];
            fv[4]=cv[2];  fv[5]=cv[3];  fv[6]=cv[4];  fv[7]=cv[5];
        } else {
            fv[0]=cv[6];  fv[1]=cv[7];  fv[2]=cv[8];  fv[3]=cv[9];
            fv[4]=cv[10]; fv[5]=cv[11]; fv[6]=cv[12]; fv[7]=cv[13];
        }
        union { unsigned u[4]; short8 s8; } a1u;
        #pragma unroll
        for (int j = 0; j < 4; ++j) a1u.u[j] = pack2_bf16(fv[2*j], fv[2*j+1]);
        const short8 a1 = a1u.s8;

        // ---- Layer 1: 4 n-tiles, K=32, bias-initialized accumulators
        f32x4 c1[4];
        #pragma unroll
        for (int t1 = 0; t1 < 4; ++t1) {
            f32x4 ci = {bv1[t1], bv1[t1], bv1[t1], bv1[t1]};
            c1[t1] = __builtin_amdgcn_mfma_f32_16x16x32_bf16(a1, B1f[t1], ci, 0, 0, 0);
        }
        // ch32 rank-1 fixup + mask coords for this lane's 4 C-rows (float4 LDS reads)
        const f32x4 v32r = *(const f32x4*)&mv32[w][lg*4];
        const f32x4 mxr  = *(const f32x4*)&mcx[w][lg*4];
        #pragma unroll
        for (int t1 = 0; t1 < 4; ++t1)
            #pragma unroll
            for (int r = 0; r < 4; ++r)
                c1[t1][r] = __builtin_fmaf(v32r[r], w32[t1], c1[t1][r]);
        #pragma unroll
        for (int t1 = 0; t1 < 4; ++t1)
            #pragma unroll
            for (int r = 0; r < 4; ++r)
                c1[t1][r] = gelu_fast(c1[t1][r]);

        // ---- transpose L1 out (C-layout) -> A-layout via LDS
        #pragma unroll
        for (int t1 = 0; t1 < 4; ++t1)
            #pragma unroll
            for (int r = 0; r < 4; ++r)
                a2buf[w][(lg*4 + r)*A2S + t1*16 + lr] = f2bf_hu(c1[t1][r]);
        short8 a2f[2];
        #pragma unroll
        for (int s = 0; s < 2; ++s)
            a2f[s] = *(const short8*)&a2buf[w][lr*A2S + s*32 + lg*8];

        // ---- Layer 2: K=64 (2 steps), 2 n-tiles
        f32x4 c2[2];
        #pragma unroll
        for (int t2 = 0; t2 < 2; ++t2) {
            f32x4 ci = {bv2[t2], bv2[t2], bv2[t2], bv2[t2]};
            ci = __builtin_amdgcn_mfma_f32_16x16x32_bf16(a2f[0], B2f[0][t2], ci, 0, 0, 0);
            c2[t2] = __builtin_amdgcn_mfma_f32_16x16x32_bf16(a2f[1], B2f[1][t2], ci, 0, 0, 0);
        }
        #pragma unroll
        for (int t2 = 0; t2 < 2; ++t2)
            #pragma unroll
            for (int r = 0; r < 4; ++r)
                c2[t2][r] = gelu_fast(c2[t2][r]);

        // ---- transpose L2 out -> A-layout, ALIASED into a2buf space (the R8 delta).
        // Safe: a2f reads are complete (data dep through MFMA) before these writes
        // issue, and same-wave DS ops process in order. (Functionally validated R6/R7.)
        unsigned short* a3p = &a2buf[w][0];
        #pragma unroll
        for (int t2 = 0; t2 < 2; ++t2)
            #pragma unroll
            for (int r = 0; r < 4; ++r)
                a3p[(lg*4 + r)*A3S + t2*16 + lr] = f2bf_hu(c2[t2][r]);
        const short8 a3f = *(const short8*)&a3p[lr*A3S + lg*8];

        // ---- Layer 3: K=32, N=16 (8 valid)
        f32x4 c3 = {bv3, bv3, bv3, bv3};
        c3 = __builtin_amdgcn_mfma_f32_16x16x32_bf16(a3f, B3f, c3, 0, 0, 0);

        // ---- tanh, mask, store per-row result to block buffer
        #pragma unroll
        for (int r = 0; r < 4; ++r) {
            const int brow = w*(TILES_PER_WAVE*16) + t*16 + lg*4 + r;
            const float mk = (fabsf(mxr[r]) > 1e-6f) ? 1.0f : 0.0f;
            if (lr < H3) obuf[brow*9 + lr] = mk * tanh_fast(c3[r]);
        }
    }

    __syncthreads();

    // ---- neighbor reduction: 32 points x 8 channels = 256 threads (R4 mapping)
    {
        const int p  = tid >> 3;   // 0..31
        const int ch = tid & 7;
        float sum = 0.0f;
        #pragma unroll
        for (int i = 0; i < PN; ++i) sum += obuf[(p*PN + i)*9 + ch];
        const int gp = blockIdx.x * PTS_PER_BLOCK + p;
        out[(size_t)ch * NPT + gp] = sum;
    }
}

extern "C" void kernel_launch(void* const* d_in, const int* in_sizes, int n_in,
                              void* d_out, int out_size, void* d_ws, size_t ws_size,
                              hipStream_t stream) {
    // setup_inputs order: x, grid(unused), freqs, W1, b1, W2, b2, W3, b3
    const float* x     = (const float*)d_in[0];
    const float* freqs = (const float*)d_in[2];
    const float* W1    = (const float*)d_in[3];
    const float* b1    = (const float*)d_in[4];
    const float* W2    = (const float*)d_in[5];
    const float* b2    = (const float*)d_in[6];
    const float* W3    = (const float*)d_in[7];
    const float* b3    = (const float*)d_in[8];
    float* out = (float*)d_out;

    const int grid = NPT / PTS_PER_BLOCK;   // 3072 blocks, no remainder
    domino_mfma_kernel<<<grid, 256, 0, stream>>>(x, freqs, W1, b1, W2, b2, W3, b3, out);
}